// Round 1
// baseline (4362.292 us; speedup 1.0000x reference)
//
#include <hip/hip_runtime.h>

// WaveNet: B=8, T=16384, RES=64, GATE=128, IN=256, OUT=256, 20 blocks, K=2.
// Scratch plan: o ping-pong buffers live inside d_out (overwritten by the
// final head which writes every element); skip lives in d_ws (needs 33.6 MB).

#define NB    20
#define RES   64
#define GATE  128
#define INC   256
#define OUTC  256
#define B_SZ  8
#define T_LEN 16384
#define TILE  64

__device__ __forceinline__ float rcp_fast(float x) {
    float r;
    asm("v_rcp_f32 %0, %1" : "=v"(r) : "v"(x));
    return r;
}
__device__ __forceinline__ float fast_sigmoid(float x) {
    // 1/(1+exp(-x)); exp(-x)->inf gives rcp(inf)=0 (correct limit), safe.
    return rcp_fast(1.0f + __expf(-x));
}
__device__ __forceinline__ float fast_tanh(float x) {
    x = fminf(fmaxf(x, -15.0f), 15.0f);   // avoid inf*0 = NaN
    float e = __expf(2.0f * x);
    return (e - 1.0f) * rcp_fast(e + 1.0f);
}

// ---------------- input layer: o = causal_conv(x^T, il_w, d=1); skip = 0 ----
__global__ __launch_bounds__(256) void k_input(
    const float* __restrict__ x, const float* __restrict__ w,
    const float* __restrict__ bias, float* __restrict__ o,
    float* __restrict__ skip)
{
    __shared__ float xs[128][66];   // [ci][r], r = 0..64 (t0-1 .. t0+63)
    const int t0  = blockIdx.x * TILE;
    const int b   = blockIdx.y;
    const int tid = threadIdx.x;
    const int tl  = tid & 63;
    const int wv  = __builtin_amdgcn_readfirstlane(tid >> 6);  // wave id (uniform)

    float acc[16];
#pragma unroll
    for (int j = 0; j < 16; ++j) acc[j] = bias[wv * 16 + j];

    for (int half = 0; half < 2; ++half) {
        const int cbase = half * 128;
        __syncthreads();   // protect xs from previous half's readers
        for (int idx = tid; idx < 128 * 65; idx += 256) {
            int ci = idx & 127;
            int r  = idx >> 7;
            int tg = t0 - 1 + r;
            float v = 0.0f;
            if (tg >= 0) v = x[((long)b * T_LEN + tg) * INC + cbase + ci];
            xs[ci][r] = v;
        }
        __syncthreads();
#pragma unroll 4
        for (int ci = 0; ci < 128; ++ci) {
            float xl = xs[ci][tl];       // tap at t-1
            float xc = xs[ci][tl + 1];   // tap at t
            const float* wp = w + (((wv * 16) * INC) + cbase + ci) * 2;
#pragma unroll
            for (int j = 0; j < 16; ++j) {
                acc[j] += wp[j * INC * 2] * xl + wp[j * INC * 2 + 1] * xc;
            }
        }
    }
#pragma unroll
    for (int j = 0; j < 16; ++j) {
        int c = wv * 16 + j;
        long base = ((long)(b * RES + c)) * T_LEN + t0 + tl;
        o[base]    = acc[j];
        skip[base] = 0.0f;
    }
}

// ---------------- residual block -------------------------------------------
__global__ __launch_bounds__(256) void k_res(
    const float* __restrict__ o_in, float* __restrict__ o_out,
    float* __restrict__ skip,
    const float* __restrict__ w1, const float* __restrict__ b1,
    const float* __restrict__ w2, const float* __restrict__ b2,
    int dilation)
{
    __shared__ float oc_s[RES][TILE];   // current tile  [ci][t]
    __shared__ float ol_s[RES][TILE];   // left-tap tile; reused as z after conv
    __shared__ float sg_s[RES][TILE];   // sigmoid(gate) rows
    const int t0  = blockIdx.x * TILE;
    const int b   = blockIdx.y;
    const int tid = threadIdx.x;
    const int tl  = tid & 63;
    const int wv  = __builtin_amdgcn_readfirstlane(tid >> 6);

    for (int idx = tid; idx < RES * TILE; idx += 256) {
        int ci = idx >> 6;
        int t  = idx & 63;
        long base = ((long)(b * RES + ci)) * T_LEN;
        oc_s[ci][t] = o_in[base + t0 + t];
        int tg = t0 - dilation + t;
        ol_s[ci][t] = (tg >= 0) ? o_in[base + tg] : 0.0f;
    }
    __syncthreads();

    // dilated conv: wave wv computes gate rows c0..c0+31
    float acc[32];
    const int c0 = wv * 32;
#pragma unroll
    for (int j = 0; j < 32; ++j) acc[j] = b1[c0 + j];
#pragma unroll 2
    for (int ci = 0; ci < RES; ++ci) {
        float vl = ol_s[ci][tl];
        float vc = oc_s[ci][tl];
        const float* wp = w1 + ((c0)*RES + ci) * 2;
#pragma unroll
        for (int j = 0; j < 32; ++j) {
            acc[j] += wp[j * RES * 2] * vl + wp[j * RES * 2 + 1] * vc;
        }
    }
    // waves 2,3 hold gate rows 64..127 -> sigmoid into sg_s
    if (wv >= 2) {
#pragma unroll
        for (int j = 0; j < 32; ++j)
            sg_s[c0 - RES + j][tl] = fast_sigmoid(acc[j]);
    }
    __syncthreads();   // all conv reads of ol_s done; sg_s ready
    // waves 0,1 hold filter rows 0..63 -> z = tanh * sig (into ol_s)
    if (wv < 2) {
#pragma unroll
        for (int j = 0; j < 32; ++j)
            ol_s[c0 + j][tl] = fast_tanh(acc[j]) * sg_s[c0 + j][tl];
    }
    __syncthreads();

    // 1x1: wave wv computes s rows wv*16..wv*16+15; update o and skip
    {
        float acc2[16];
        const int d0 = wv * 16;
#pragma unroll
        for (int j = 0; j < 16; ++j) acc2[j] = b2[d0 + j];
#pragma unroll 4
        for (int ci = 0; ci < RES; ++ci) {
            float zv = ol_s[ci][tl];
            const float* wp = w2 + d0 * RES + ci;
#pragma unroll
            for (int j = 0; j < 16; ++j) acc2[j] += wp[j * RES] * zv;
        }
#pragma unroll
        for (int j = 0; j < 16; ++j) {
            int c = d0 + j;
            long base = ((long)(b * RES + c)) * T_LEN + t0 + tl;
            float s = acc2[j];
            o_out[base] = oc_s[c][tl] + s;
            skip[base] += s;
        }
    }
}

// ---------------- output head: out = relu(relu(skip)@W1+b1)@W2+b2 ----------
__global__ __launch_bounds__(256) void k_out(
    const float* __restrict__ skip,
    const float* __restrict__ w1, const float* __restrict__ b1,
    const float* __restrict__ w2, const float* __restrict__ b2,
    float* __restrict__ out)
{
    __shared__ float t1buf[OUTC][TILE];   // 64 KB, relu(t1) [ci][t]
    const int t0  = blockIdx.x * TILE;
    const int b   = blockIdx.y;
    const int tid = threadIdx.x;
    const int tl  = tid & 63;
    const int wv  = __builtin_amdgcn_readfirstlane(tid >> 6);

    // per-thread column of relu(skip) in registers (static indexing only)
    float srel[RES];
#pragma unroll
    for (int ci = 0; ci < RES; ++ci) {
        float v = skip[((long)(b * RES + ci)) * T_LEN + t0 + tl];
        srel[ci] = fmaxf(v, 0.0f);
    }

    const int c0 = wv * 64;   // this wave's 64 rows (of 256)
#pragma unroll 1
    for (int j0 = 0; j0 < 64; j0 += 8) {
        float acc[8];
#pragma unroll
        for (int j = 0; j < 8; ++j) acc[j] = b1[c0 + j0 + j];
#pragma unroll
        for (int ci = 0; ci < RES; ++ci) {
            float v = srel[ci];
            const float* wp = w1 + (c0 + j0) * RES + ci;
#pragma unroll
            for (int j = 0; j < 8; ++j) acc[j] += wp[j * RES] * v;
        }
#pragma unroll
        for (int j = 0; j < 8; ++j)
            t1buf[c0 + j0 + j][tl] = fmaxf(acc[j], 0.0f);
    }
    __syncthreads();

#pragma unroll 1
    for (int j0 = 0; j0 < 64; j0 += 16) {
        float acc[16];
#pragma unroll
        for (int j = 0; j < 16; ++j) acc[j] = b2[c0 + j0 + j];
#pragma unroll 2
        for (int ci = 0; ci < OUTC; ++ci) {
            float v = t1buf[ci][tl];
            const float* wp = w2 + (c0 + j0) * OUTC + ci;
#pragma unroll
            for (int j = 0; j < 16; ++j) acc[j] += wp[j * OUTC] * v;
        }
#pragma unroll
        for (int j = 0; j < 16; ++j) {
            out[((long)(b * OUTC + c0 + j0 + j)) * T_LEN + t0 + tl] = acc[j];
        }
    }
}

extern "C" void kernel_launch(void* const* d_in, const int* in_sizes, int n_in,
                              void* d_out, int out_size, void* d_ws, size_t ws_size,
                              hipStream_t stream)
{
    const float* x     = (const float*)d_in[0];
    const float* il_w  = (const float*)d_in[1];
    const float* il_b  = (const float*)d_in[2];
    const float* rb_w1 = (const float*)d_in[3];
    const float* rb_b1 = (const float*)d_in[4];
    const float* rb_w2 = (const float*)d_in[5];
    const float* rb_b2 = (const float*)d_in[6];
    const float* ol_w1 = (const float*)d_in[7];
    const float* ol_b1 = (const float*)d_in[8];
    const float* ol_w2 = (const float*)d_in[9];
    const float* ol_b2 = (const float*)d_in[10];
    float* out = (float*)d_out;

    const size_t plane = (size_t)B_SZ * RES * T_LEN;   // 8.39 M floats
    // o ping-pong inside d_out (out_size = 4*plane elements); skip in d_ws.
    float* oA   = out;               // [0, plane)
    float* oB   = out + plane;       // [plane, 2*plane)
    float* skip = (float*)d_ws;      // needs plane*4 = 33.6 MB of ws

    dim3 grid(T_LEN / TILE, B_SZ);
    dim3 block(256);

    k_input<<<grid, block, 0, stream>>>(x, il_w, il_b, oA, skip);

    float* cur = oA;
    float* nxt = oB;
    for (int i = 0; i < NB; ++i) {
        int dil = 1 << (i % 10);
        k_res<<<grid, block, 0, stream>>>(
            cur, nxt, skip,
            rb_w1 + (size_t)i * GATE * RES * 2, rb_b1 + i * GATE,
            rb_w2 + (size_t)i * RES * RES,      rb_b2 + i * RES, dil);
        float* tmp = cur; cur = nxt; nxt = tmp;
    }

    k_out<<<grid, block, 0, stream>>>(skip, ol_w1, ol_b1, ol_w2, ol_b2, out);
}

// Round 3
// 984.982 us; speedup vs baseline: 4.4288x; 4.4288x over previous
//
#include <hip/hip_runtime.h>

// WaveNet B=8 T=16384 RES=64 GATE=128 IN=256 OUT=256, 20 blocks, K=2.
// bf16 MFMA (16x16x32) everywhere. Activations channel-last bf16 [B][T][C]
// (= row-major [N][K] -> B-frags are contiguous 16B loads). Res-stack weights
// packed once per launch to bf16 [M][K] in d_out+40MiB (only read by k_in /
// k_res, whose output regions are disjoint -> race-free). k_head converts the
// fp32 head weights inline (it overwrites all of d_out, so it must not read
// packed weights from there). skip stays fp32 in d_ws (33.55 MB).

#define NB    20
#define RES   64
#define GATE  128
#define INC   256
#define OUTC  256
#define B_SZ  8
#define T_LEN 16384

typedef short s16x4 __attribute__((ext_vector_type(4)));
typedef short s16x8 __attribute__((ext_vector_type(8)));
typedef float f32x4 __attribute__((ext_vector_type(4)));

#define MFMA(a, b, c) __builtin_amdgcn_mfma_f32_16x16x32_bf16((a), (b), (c), 0, 0, 0)

// packed-weight offsets (in shorts) inside the pack region (res stack only)
#define OFF_W0   0         // il_w   [64][512]      k = tap*256+ci
#define OFF_W1   32768     // rb_w1  [20][128][128] k = tap*64+ci
#define OFF_W2   360448    // rb_w2  [20][64][64]
#define PACK_N   442368

__device__ __forceinline__ short f2bf(float f) {
    union { float f; unsigned u; } v; v.f = f;
    unsigned r = v.u + 0x7FFFu + ((v.u >> 16) & 1u);
    return (short)(r >> 16);
}
__device__ __forceinline__ float bf2f(short s) {
    union { unsigned u; float f; } v;
    v.u = ((unsigned)(unsigned short)s) << 16;
    return v.f;
}
__device__ __forceinline__ float rcp_fast(float x) {
    float r; asm("v_rcp_f32 %0, %1" : "=v"(r) : "v"(x)); return r;
}
__device__ __forceinline__ float fast_sigmoid(float x) {
    return rcp_fast(1.0f + __expf(-x));
}
__device__ __forceinline__ float fast_tanh(float x) {
    x = fminf(fmaxf(x, -15.0f), 15.0f);
    float e = __expf(2.0f * x);
    return (e - 1.0f) * rcp_fast(e + 1.0f);
}

// ---------------- weight pack: fp32 -> bf16, tap-deinterleave (res stack) ---
__global__ __launch_bounds__(256) void k_pack(
    const float* __restrict__ il_w, const float* __restrict__ w1,
    const float* __restrict__ w2, short* __restrict__ dst)
{
    for (int idx = blockIdx.x * 256 + threadIdx.x; idx < PACK_N; idx += 512 * 256) {
        float v;
        if (idx < OFF_W1) {                       // il_w [64][256][2] -> [64][tap*256+ci]
            int m = idx >> 9, k = idx & 511, tap = k >> 8, ci = k & 255;
            v = il_w[(m * 256 + ci) * 2 + tap];
        } else if (idx < OFF_W2) {                // rb_w1 [L][128][64][2] -> [L][128][tap*64+ci]
            int j = idx - OFF_W1;
            int L = j >> 14, r = j & 16383;
            int m = r >> 7, k = r & 127, tap = k >> 6, ci = k & 63;
            v = w1[L * 16384 + (m * 64 + ci) * 2 + tap];
        } else {
            v = w2[idx - OFF_W2];
        }
        dst[idx] = f2bf(v);
    }
}

// ---------------- zero skip ------------------------------------------------
__global__ __launch_bounds__(256) void k_zero(f32x4* __restrict__ p) {
    int i = blockIdx.x * 256 + threadIdx.x;   // grid covers exactly 2097152
    p[i] = (f32x4)0.0f;
}

// ---------------- input layer: o[b][t][64] = conv(x, d=1) ------------------
__global__ __launch_bounds__(256, 4) void k_in(
    const float* __restrict__ x, const short* __restrict__ w0p,
    const float* __restrict__ bias, short* __restrict__ o)
{
    __shared__ short Xs[129][132];   // rows: t0-1 .. t0+127 ; 128-ch chunk
    const int t0 = blockIdx.x * 128;
    const int b  = blockIdx.y;
    const int tid = threadIdx.x;
    const int w = tid >> 6, ln = tid & 63, tl = ln & 15, g = ln >> 4;
    const int tw = w * 32;

    f32x4 acc[4][2];
#pragma unroll
    for (int mt = 0; mt < 4; ++mt) {
        f32x4 bv = *(const f32x4*)(bias + mt * 16 + g * 4);
        acc[mt][0] = bv; acc[mt][1] = bv;
    }

    for (int c = 0; c < 2; ++c) {
        __syncthreads();
        for (int idx = tid; idx < 129 * 32; idx += 256) {
            int r = idx >> 5, c4 = (idx & 31) * 4;
            int tg = t0 - 1 + r;
            f32x4 v = (f32x4)0.0f;
            if (tg >= 0)
                v = *(const f32x4*)(x + ((size_t)b * T_LEN + tg) * INC + c * 128 + c4);
            s16x4 sv;
#pragma unroll
            for (int j = 0; j < 4; ++j) sv[j] = f2bf(v[j]);
            *(s16x4*)&Xs[r][c4] = sv;
        }
        __syncthreads();
#pragma unroll
        for (int ks = 0; ks < 8; ++ks) {
            int tap = ks >> 2;               // 0: x[t-1]  1: x[t]
            int ci  = (ks & 3) * 32 + g * 8;
            s16x8 bfr[2];
#pragma unroll
            for (int nf = 0; nf < 2; ++nf) {
                int row = tw + nf * 16 + tl + tap;
                s16x4 lo = *(const s16x4*)&Xs[row][ci];
                s16x4 hi = *(const s16x4*)&Xs[row][ci + 4];
                bfr[nf] = __builtin_shufflevector(lo, hi, 0, 1, 2, 3, 4, 5, 6, 7);
            }
#pragma unroll
            for (int mt = 0; mt < 4; ++mt) {
                const s16x8 a = *(const s16x8*)(
                    w0p + (size_t)(mt * 16 + tl) * 512 + tap * 256 + c * 128 + (ks & 3) * 32 + g * 8);
                acc[mt][0] = MFMA(a, bfr[0], acc[mt][0]);
                acc[mt][1] = MFMA(a, bfr[1], acc[mt][1]);
            }
        }
    }
#pragma unroll
    for (int mt = 0; mt < 4; ++mt)
#pragma unroll
        for (int nf = 0; nf < 2; ++nf) {
            int t = t0 + tw + nf * 16 + tl;
            s16x4 ov;
#pragma unroll
            for (int r = 0; r < 4; ++r) ov[r] = f2bf(acc[mt][nf][r]);
            *(s16x4*)(o + ((size_t)b * T_LEN + t) * RES + mt * 16 + g * 4) = ov;
        }
}

// ---------------- residual block (barrier-free, wave owns 64 t) ------------
__global__ __launch_bounds__(256, 2) void k_res(
    const short* __restrict__ o_in, short* __restrict__ o_out,
    float* __restrict__ skip,
    const short* __restrict__ w1p, const short* __restrict__ w2p,
    const float* __restrict__ b1, const float* __restrict__ b2, int dil)
{
    __shared__ short Zs[256][68];   // z tile [t][ch], per-wave private rows
    const int t0 = blockIdx.x * 256;
    const int b  = blockIdx.y;
    const int tid = threadIdx.x;
    const int w = tid >> 6, ln = tid & 63, tl = ln & 15, g = ln >> 4;
    const int tw = w * 64;
    const size_t ob = (size_t)b * T_LEN * RES;

    // B-frags: k = tap*64+ci ; ks 0,1 = left tap (t-d), 2,3 = center
    s16x8 bfr[4][4];
#pragma unroll
    for (int nf = 0; nf < 4; ++nf) {
        int t = t0 + tw + nf * 16 + tl;
#pragma unroll
        for (int ks = 0; ks < 4; ++ks) {
            int ts = (ks >= 2) ? t : t - dil;
            int ci = (ks & 1) * 32 + g * 8;
            if (ts >= 0) bfr[nf][ks] = *(const s16x8*)(o_in + ob + (size_t)ts * RES + ci);
            else         bfr[nf][ks] = (s16x8)0;
        }
    }

    // GEMM1 (gate conv) + gating; pair (mp, mp+4) = (filter rows, gate rows)
#pragma unroll
    for (int mp = 0; mp < 4; ++mp) {
        f32x4 accA[4], accG[4];
        f32x4 bA = *(const f32x4*)(b1 + mp * 16 + g * 4);
        f32x4 bG = *(const f32x4*)(b1 + 64 + mp * 16 + g * 4);
#pragma unroll
        for (int nf = 0; nf < 4; ++nf) { accA[nf] = bA; accG[nf] = bG; }
#pragma unroll
        for (int ks = 0; ks < 4; ++ks) {
            const s16x8 aA = *(const s16x8*)(w1p + (size_t)(mp * 16 + tl) * 128 + ks * 32 + g * 8);
            const s16x8 aG = *(const s16x8*)(w1p + (size_t)((mp + 4) * 16 + tl) * 128 + ks * 32 + g * 8);
#pragma unroll
            for (int nf = 0; nf < 4; ++nf) {
                accA[nf] = MFMA(aA, bfr[nf][ks], accA[nf]);
                accG[nf] = MFMA(aG, bfr[nf][ks], accG[nf]);
            }
        }
#pragma unroll
        for (int nf = 0; nf < 4; ++nf) {
            s16x4 zv;
#pragma unroll
            for (int r = 0; r < 4; ++r)
                zv[r] = f2bf(fast_tanh(accA[nf][r]) * fast_sigmoid(accG[nf][r]));
            *(s16x4*)&Zs[tw + nf * 16 + tl][mp * 16 + g * 4] = zv;
        }
    }

    // GEMM2 (1x1): s = W2 x z   (same-wave LDS rows only -> no barrier)
    f32x4 acc2[4][4];
#pragma unroll
    for (int mt = 0; mt < 4; ++mt) {
        f32x4 bv = *(const f32x4*)(b2 + mt * 16 + g * 4);
#pragma unroll
        for (int nf = 0; nf < 4; ++nf) acc2[mt][nf] = bv;
    }
#pragma unroll
    for (int ks = 0; ks < 2; ++ks) {
        s16x8 bz[4];
#pragma unroll
        for (int nf = 0; nf < 4; ++nf) {
            s16x4 lo = *(const s16x4*)&Zs[tw + nf * 16 + tl][ks * 32 + g * 8];
            s16x4 hi = *(const s16x4*)&Zs[tw + nf * 16 + tl][ks * 32 + g * 8 + 4];
            bz[nf] = __builtin_shufflevector(lo, hi, 0, 1, 2, 3, 4, 5, 6, 7);
        }
#pragma unroll
        for (int mt = 0; mt < 4; ++mt) {
            const s16x8 a2 = *(const s16x8*)(w2p + (size_t)(mt * 16 + tl) * 64 + ks * 32 + g * 8);
#pragma unroll
            for (int nf = 0; nf < 4; ++nf) acc2[mt][nf] = MFMA(a2, bz[nf], acc2[mt][nf]);
        }
    }
    // epilogue: o_out = o_in + s ; skip += s
#pragma unroll
    for (int mt = 0; mt < 4; ++mt)
#pragma unroll
        for (int nf = 0; nf < 4; ++nf) {
            int t = t0 + tw + nf * 16 + tl;
            size_t base = ob + (size_t)t * RES + mt * 16 + g * 4;
            s16x4 ov = *(const s16x4*)(o_in + base);
            f32x4 sk = *(f32x4*)(skip + base);
            s16x4 nv;
#pragma unroll
            for (int r = 0; r < 4; ++r) {
                float s = acc2[mt][nf][r];
                nv[r] = f2bf(bf2f(ov[r]) + s);
                sk[r] += s;
            }
            *(s16x4*)(o_out + base) = nv;
            *(f32x4*)(skip + base) = sk;
        }
}

// ---------------- output head ---------------------------------------------
// Reads fp32 head weights directly (d_out is being overwritten by this very
// kernel, so no packed weights may live there). A-frags converted inline.
__device__ __forceinline__ s16x8 ldw_bf16(const float* p) {
    f32x4 u0 = *(const f32x4*)p;
    f32x4 u1 = *(const f32x4*)(p + 4);
    s16x8 v;
#pragma unroll
    for (int j = 0; j < 4; ++j) { v[j] = f2bf(u0[j]); v[j + 4] = f2bf(u1[j]); }
    return v;
}

__global__ __launch_bounds__(256, 3) void k_head(
    const float* __restrict__ skip,
    const float* __restrict__ w1, const float* __restrict__ b1h,
    const float* __restrict__ w2, const float* __restrict__ b2h,
    float* __restrict__ out)
{
    __shared__ short T1[64][260];   // relu(t1) [t][ch 0..255]
    const int t0 = blockIdx.x * 64;
    const int b  = blockIdx.y;
    const int tid = threadIdx.x;
    const int w = tid >> 6, ln = tid & 63, tl = ln & 15, g = ln >> 4;
    const int m0 = w * 64;

    // GEMM1: t1 = relu(skip) @ W1h  (K=64)  w1: [256][64] row-major fp32
    f32x4 acc1[4][4];
#pragma unroll
    for (int mt = 0; mt < 4; ++mt) {
        f32x4 bv = *(const f32x4*)(b1h + m0 + mt * 16 + g * 4);
#pragma unroll
        for (int nf = 0; nf < 4; ++nf) acc1[mt][nf] = bv;
    }
#pragma unroll
    for (int ks = 0; ks < 2; ++ks) {
        s16x8 bs[4];
#pragma unroll
        for (int nf = 0; nf < 4; ++nf) {
            int t = t0 + nf * 16 + tl;
            const float* sp = skip + ((size_t)b * T_LEN + t) * RES + ks * 32 + g * 8;
            f32x4 u0 = *(const f32x4*)sp;
            f32x4 u1 = *(const f32x4*)(sp + 4);
            s16x8 v;
#pragma unroll
            for (int j = 0; j < 4; ++j) {
                v[j]     = f2bf(fmaxf(u0[j], 0.0f));
                v[j + 4] = f2bf(fmaxf(u1[j], 0.0f));
            }
            bs[nf] = v;
        }
#pragma unroll
        for (int mt = 0; mt < 4; ++mt) {
            const s16x8 a = ldw_bf16(w1 + (size_t)(m0 + mt * 16 + tl) * 64 + ks * 32 + g * 8);
#pragma unroll
            for (int nf = 0; nf < 4; ++nf) acc1[mt][nf] = MFMA(a, bs[nf], acc1[mt][nf]);
        }
    }
#pragma unroll
    for (int mt = 0; mt < 4; ++mt)
#pragma unroll
        for (int nf = 0; nf < 4; ++nf) {
            int tloc = nf * 16 + tl;
            s16x4 zv;
#pragma unroll
            for (int r = 0; r < 4; ++r) zv[r] = f2bf(fmaxf(acc1[mt][nf][r], 0.0f));
            *(s16x4*)&T1[tloc][m0 + mt * 16 + g * 4] = zv;
        }
    __syncthreads();

    // GEMM2: out = relu(t1) @ W2h  (K=256)  w2: [256][256] row-major fp32
    f32x4 acc2[4][4];
#pragma unroll
    for (int mt = 0; mt < 4; ++mt) {
        f32x4 bv = *(const f32x4*)(b2h + m0 + mt * 16 + g * 4);
#pragma unroll
        for (int nf = 0; nf < 4; ++nf) acc2[mt][nf] = bv;
    }
#pragma unroll
    for (int ks = 0; ks < 8; ++ks) {
        s16x8 bz[4];
#pragma unroll
        for (int nf = 0; nf < 4; ++nf) {
            s16x4 lo = *(const s16x4*)&T1[nf * 16 + tl][ks * 32 + g * 8];
            s16x4 hi = *(const s16x4*)&T1[nf * 16 + tl][ks * 32 + g * 8 + 4];
            bz[nf] = __builtin_shufflevector(lo, hi, 0, 1, 2, 3, 4, 5, 6, 7);
        }
#pragma unroll
        for (int mt = 0; mt < 4; ++mt) {
            const s16x8 a = ldw_bf16(w2 + (size_t)(m0 + mt * 16 + tl) * 256 + ks * 32 + g * 8);
#pragma unroll
            for (int nf = 0; nf < 4; ++nf) acc2[mt][nf] = MFMA(a, bz[nf], acc2[mt][nf]);
        }
    }
#pragma unroll
    for (int mt = 0; mt < 4; ++mt)
#pragma unroll
        for (int nf = 0; nf < 4; ++nf) {
            int t = t0 + nf * 16 + tl;
#pragma unroll
            for (int r = 0; r < 4; ++r) {
                int ch = m0 + mt * 16 + g * 4 + r;
                out[((size_t)b * OUTC + ch) * T_LEN + t] = acc2[mt][nf][r];
            }
        }
}

extern "C" void kernel_launch(void* const* d_in, const int* in_sizes, int n_in,
                              void* d_out, int out_size, void* d_ws, size_t ws_size,
                              hipStream_t stream)
{
    const float* x     = (const float*)d_in[0];
    const float* il_w  = (const float*)d_in[1];
    const float* il_b  = (const float*)d_in[2];
    const float* rb_w1 = (const float*)d_in[3];
    const float* rb_b1 = (const float*)d_in[4];
    const float* rb_w2 = (const float*)d_in[5];
    const float* rb_b2 = (const float*)d_in[6];
    const float* ol_w1 = (const float*)d_in[7];
    const float* ol_b1 = (const float*)d_in[8];
    const float* ol_w2 = (const float*)d_in[9];
    const float* ol_b2 = (const float*)d_in[10];

    char*  outc = (char*)d_out;
    short* oA   = (short*)outc;                        // 16 MiB  (o ping)
    short* oB   = (short*)(outc + (16u << 20));        // 16 MiB  (o pong)
    short* wpk  = (short*)(outc + (40u << 20));        // <1 MiB packed res weights
    float* skip = (float*)d_ws;                        // 33.55 MB fp32
    float* out  = (float*)d_out;

    dim3 blk(256);

    k_pack<<<dim3(512), blk, 0, stream>>>(il_w, rb_w1, rb_w2, wpk);
    k_zero<<<dim3(8192), blk, 0, stream>>>((f32x4*)skip);
    k_in<<<dim3(T_LEN / 128, B_SZ), blk, 0, stream>>>(x, wpk + OFF_W0, il_b, oA);

    short* cur = oA;
    short* nxt = oB;
    for (int i = 0; i < NB; ++i) {
        int dil = 1 << (i % 10);
        k_res<<<dim3(T_LEN / 256, B_SZ), blk, 0, stream>>>(
            cur, nxt, skip,
            wpk + OFF_W1 + (size_t)i * 16384, wpk + OFF_W2 + (size_t)i * 4096,
            rb_b1 + i * GATE, rb_b2 + i * RES, dil);
        short* tmp = cur; cur = nxt; nxt = tmp;
    }

    k_head<<<dim3(T_LEN / 64, B_SZ), blk, 0, stream>>>(
        skip, ol_w1, ol_b1, ol_w2, ol_b2, out);
}